// Round 14
// baseline (607.415 us; speedup 1.0000x reference)
//
#include <hip/hip_runtime.h>
#include <hip/hip_cooperative_groups.h>

namespace cg = cooperative_groups;

// Sparse voxel downsample (FACTOR=2, RES=256 -> res=128, B=2, C=64).
// code = ((b*128 + x/2)*128 + y/2)*128 + z/2  in [0, 4194304)
// ONE cooperative preamble kernel (zero -> count -> block sums -> scan ->
// scan-write -> counting-sort) with grid.sync() between phases, then the
// validated gather16 hot pass: random 256B reads (L3-warm feats), NT
// sequential writes, 4 chains/quarter-wave, in-register mean, no atomics.

#define RES2 128
#define NCODES (2 * 128 * 128 * 128)   // 4194304 codes
#define NW (NCODES / 4)                // 1048576 u32 words in u8 histogram
#define PBLK 1024                      // cooperative grid: 1024 blocks x 256
#define PTHREADS (PBLK * 256)          // 262144 = NW/4 exactly

typedef unsigned long long u64;
typedef float f4 __attribute__((ext_vector_type(4)));

__device__ __forceinline__ u64 pack_word(unsigned w) {
    unsigned b0 = w & 0xFFu, b1 = (w >> 8) & 0xFFu,
             b2 = (w >> 16) & 0xFFu, b3 = w >> 24;
    return ((u64)(b0 + b1 + b2 + b3) << 32) |
           (u64)((b0 != 0) + (b1 != 0) + (b2 != 0) + (b3 != 0));
}

// Fused preamble. Layout: thread t of block b owns words [b*1024+t*4, +4).
__global__ void preamble(const int* __restrict__ coords,
                         unsigned* __restrict__ cnt8,
                         int* __restrict__ codes,
                         u64* __restrict__ btot,
                         unsigned* __restrict__ nuq,
                         unsigned* __restrict__ wprefix,
                         unsigned* __restrict__ uniq_cc,
                         unsigned* __restrict__ row_end,
                         int* __restrict__ sorted_idx, int n) {
    cg::grid_group grid = cg::this_grid();
    __shared__ u64 sh[256];
    const int t = threadIdx.x;
    const int b = blockIdx.x;
    const int gtid = b * 256 + t;

    // ---- P0: zero cnt8 (one uint4 per thread) ----
    reinterpret_cast<uint4*>(cnt8)[gtid] = make_uint4(0u, 0u, 0u, 0u);
    grid.sync();

    // ---- P1: histogram + code cache ----
    for (int i = gtid; i < n; i += PTHREADS) {
        const int4 v = reinterpret_cast<const int4*>(coords)[i];
        int code = (((v.x * RES2 + (v.y >> 1)) * RES2 + (v.z >> 1)) * RES2) + (v.w >> 1);
        codes[i] = code;
        atomicAdd(&cnt8[code >> 2], 1u << (8 * (code & 3)));
    }
    grid.sync();

    // ---- P2: per-block packed totals (1024 words per block) ----
    const int w4i = gtid;   // uint4 index into cnt8
    {
        const uint4 w = reinterpret_cast<const uint4*>(cnt8)[w4i];
        u64 s = pack_word(w.x) + pack_word(w.y) + pack_word(w.z) + pack_word(w.w);
        sh[t] = s;
        __syncthreads();
        for (int off = 128; off > 0; off >>= 1) {
            if (t < off) sh[t] += sh[t + off];
            __syncthreads();
        }
        if (t == 0) btot[b] = sh[0];
    }
    grid.sync();

    // ---- P3: block 0 exclusive-scans the 1024 block totals ----
    if (b == 0) {
        int base = t * 4;
        u64 v[4], e[4], s = 0;
#pragma unroll
        for (int j = 0; j < 4; ++j) { v[j] = btot[base + j]; e[j] = s; s += v[j]; }
        sh[t] = s;
        __syncthreads();
        for (int off = 1; off < 256; off <<= 1) {
            u64 add = (t >= off) ? sh[t - off] : 0ull;
            __syncthreads();
            sh[t] += add;
            __syncthreads();
        }
        u64 excl = (t == 0) ? 0ull : sh[t - 1];
#pragma unroll
        for (int j = 0; j < 4; ++j) btot[base + j] = excl + e[j];
        if (t == 255) *nuq = (unsigned)(sh[255] & 0xFFFFFFFFull);
    }
    grid.sync();

    // ---- P4: local rescan + base -> wprefix, uniq_cc, row_end ----
    {
        const uint4 w = reinterpret_cast<const uint4*>(cnt8)[w4i];
        unsigned ws[4] = {w.x, w.y, w.z, w.w};
        u64 pw[4], tot = 0;
#pragma unroll
        for (int j = 0; j < 4; ++j) { pw[j] = pack_word(ws[j]); tot += pw[j]; }
        sh[t] = tot;
        __syncthreads();
        for (int off = 1; off < 256; off <<= 1) {
            u64 add = (t >= off) ? sh[t - off] : 0ull;
            __syncthreads();
            sh[t] += add;
            __syncthreads();
        }
        u64 run = ((t == 0) ? 0ull : sh[t - 1]) + btot[b];
        uint4 wp;
#pragma unroll
        for (int j = 0; j < 4; ++j) {
            unsigned flagbase = (unsigned)(run & 0xFFFFFFFFull);
            unsigned stbase = (unsigned)(run >> 32);
            ((unsigned*)&wp)[j] = flagbase;
            int code0 = (w4i * 4 + j) * 4;
            unsigned occ = 0, csum = 0;
#pragma unroll
            for (int jj = 0; jj < 4; ++jj) {
                unsigned cnt = (ws[j] >> (8 * jj)) & 0xFFu;
                if (cnt) {
                    unsigned r = flagbase + occ;
                    uniq_cc[r] = (unsigned)(code0 + jj) | (cnt << 22);
                    row_end[r] = stbase + csum;
                }
                occ += (cnt != 0);
                csum += cnt;
            }
            run += pw[j];
        }
        reinterpret_cast<uint4*>(wprefix)[w4i] = wp;
    }
    grid.sync();

    // ---- P5: counting sort of indices by rank ----
    for (int i = gtid; i < n; i += PTHREADS) {
        int c = codes[i];
        unsigned w = cnt8[c >> 2];
        unsigned base = wprefix[c >> 2];
        int j = c & 3;
        unsigned occ = 0;
        if (j > 0) occ += ((w & 0xFFu) != 0);
        if (j > 1) occ += (((w >> 8) & 0xFFu) != 0);
        if (j > 2) occ += (((w >> 16) & 0xFFu) != 0);
        unsigned r = base + occ;
        unsigned pos = atomicAdd(&row_end[r], 1u);
        sorted_idx[pos] = i;
    }
}

// Hot pass: 16 output rows per wave (quarter-wave = one 256B row, 4 batches
// = measured-optimal MLP depth). Regular loads (L3-warm feats), NT stores.
__global__ void gather16(const f4* __restrict__ feats4,
                         const int* __restrict__ sorted_idx,
                         const unsigned* __restrict__ row_end,
                         const unsigned* __restrict__ uniq_cc,
                         const unsigned* __restrict__ nuq_p,
                         f4* __restrict__ outF4,
                         f4* __restrict__ outC4, int n) {
    int tid = blockIdx.x * 256 + threadIdx.x;
    int wave = tid >> 6;
    int lane = threadIdx.x & 63;
    int q = lane >> 4;
    int sub = lane & 15;
    int rb = wave * 16 + q;
    int nuq = (int)*nuq_p;

    if (rb + 12 < nuq) {   // fast path: all 4 rows valid
        int r[4];
        unsigned en[4], cc[4];
#pragma unroll
        for (int k = 0; k < 4; ++k) r[k] = rb + k * 4;
#pragma unroll
        for (int k = 0; k < 4; ++k) en[k] = row_end[r[k]];
#pragma unroll
        for (int k = 0; k < 4; ++k) cc[k] = uniq_cc[r[k]];
        int cnt[4], st[4], i0[4];
#pragma unroll
        for (int k = 0; k < 4; ++k) {
            cnt[k] = (int)(cc[k] >> 22);
            st[k] = (int)en[k] - cnt[k];
        }
#pragma unroll
        for (int k = 0; k < 4; ++k) i0[k] = sorted_idx[st[k]];
        f4 a[4];
#pragma unroll
        for (int k = 0; k < 4; ++k)
            a[k] = feats4[(size_t)i0[k] * 16 + sub];
#pragma unroll
        for (int k = 0; k < 4; ++k) {
            if (cnt[k] > 1) {
                for (int m = 1; m < cnt[k]; ++m) {
                    int i = sorted_idx[st[k] + m];
                    a[k] += feats4[(size_t)i * 16 + sub];
                }
                a[k] *= (1.0f / (float)cnt[k]);
            }
            __builtin_nontemporal_store(a[k], &outF4[(size_t)r[k] * 16 + sub]);
            if (sub == 0) {
                unsigned code = cc[k] & 0x3FFFFFu;
                f4 cv = {(float)(code >> 21), (float)((code >> 14) & 127),
                         (float)((code >> 7) & 127), (float)(code & 127)};
                __builtin_nontemporal_store(cv, &outC4[r[k]]);
            }
        }
    } else {
#pragma unroll
        for (int k = 0; k < 4; ++k) {
            int r = rb + k * 4;
            if (r >= n) continue;
            if (r < nuq) {
                unsigned en = row_end[r];
                unsigned cc = uniq_cc[r];
                int cnt = (int)(cc >> 22);
                int st = (int)en - cnt;
                f4 a = {0.f, 0.f, 0.f, 0.f};
                for (int m = 0; m < cnt; ++m) {
                    int i = sorted_idx[st + m];
                    a += feats4[(size_t)i * 16 + sub];
                }
                a *= (1.0f / (float)cnt);
                outF4[(size_t)r * 16 + sub] = a;
                if (sub == 0) {
                    unsigned code = cc & 0x3FFFFFu;
                    f4 cv = {(float)(code >> 21), (float)((code >> 14) & 127),
                             (float)((code >> 7) & 127), (float)(code & 127)};
                    outC4[r] = cv;
                }
            } else {
                f4 zz = {0.f, 0.f, 0.f, 0.f};
                outF4[(size_t)r * 16 + sub] = zz;
                if (sub == 0) {
                    f4 mm = {-1.f, -1.f, -1.f, -1.f};
                    outC4[r] = mm;
                }
            }
        }
    }
}

extern "C" void kernel_launch(void* const* d_in, const int* in_sizes, int n_in,
                              void* d_out, int out_size, void* d_ws, size_t ws_size,
                              hipStream_t stream) {
    const float* feats = (const float*)d_in[0];
    const int* coords = (const int*)d_in[1];
    int n = in_sizes[1] / 4;   // N = 500000

    float* outF = (float*)d_out;
    f4* outC4 = (f4*)(outF + (size_t)n * 64);

    unsigned* cnt8 = (unsigned*)d_ws;              // NW u32 (4.19 MB), 16-al
    u64* btot = (u64*)(cnt8 + NW);                 // 1024 u64
    unsigned* nuq = (unsigned*)(btot + PBLK);      // 1 (+3 pad)
    int* codes = (int*)(nuq + 4);                  // n
    unsigned* wprefix = (unsigned*)(codes + n);    // NW u32 (4.19 MB), 16-al
    unsigned* uniq_cc = wprefix + NW;              // n
    unsigned* row_end = uniq_cc + n;               // n
    int* sorted_idx = (int*)(row_end + n);         // n

    void* args[] = {(void*)&coords, (void*)&cnt8, (void*)&codes,
                    (void*)&btot, (void*)&nuq, (void*)&wprefix,
                    (void*)&uniq_cc, (void*)&row_end, (void*)&sorted_idx,
                    (void*)&n};
    (void)hipLaunchCooperativeKernel((const void*)preamble,
                                     dim3(PBLK), dim3(256), args, 0, stream);

    int waves = (n + 15) / 16;
    int blocks = (waves * 64 + 255) / 256;
    gather16<<<blocks, 256, 0, stream>>>((const f4*)feats, sorted_idx,
                                         row_end, uniq_cc, nuq,
                                         (f4*)outF, outC4, n);
}